// Round 1
// baseline (83.594 us; speedup 1.0000x reference)
//
#include <hip/hip_runtime.h>

// ArcShapeRadiusConfigVisibleNeighDist — N=8192 pairwise visible-neighbour
// mean distance -> radius regression.
//
// Math note: in_sight = wrap(atan2(rel)-heading) in [-35deg, 35deg)
//   <=>  (rel . h_unit) >= cos(35deg) * |rel|      (measure-zero boundary diff)
// Diagonal (j==i): rel=0 -> 0 >= 0 passes with dist 0; we subtract 1 from the
// count after the reduction instead of testing j!=i per pair.

constexpr float COS_HALF_ANGLE = 0.8191520442889918f; // cos(35 deg)
constexpr float MIN_R = 0.5f, MAX_R = 4.0f;
constexpr float MIN_D = 0.2f, MAX_D = 5.0f;

__global__ __launch_bounds__(256) void arc_radius_kernel(
    const float* __restrict__ past,
    const float* __restrict__ pos,
    const int* __restrict__ indexes,
    const float* __restrict__ all_radii,
    float* __restrict__ out,
    int n)
{
    const int lane = threadIdx.x & 63;
    const int wave = threadIdx.x >> 6;
    const int i = blockIdx.x * 4 + wave;   // one wave per output row
    if (i >= n) return;

    // heading unit vector for row i (uniform across the wave)
    const float pix = pos[2 * i + 0];
    const float piy = pos[2 * i + 1];
    const float dx = pix - past[2 * i + 0];
    const float dy = piy - past[2 * i + 1];
    const float d2 = dx * dx + dy * dy;
    const float rlen = (d2 > 0.f) ? __builtin_amdgcn_rsqf(d2) : 0.f;
    const float hx = (d2 > 0.f) ? dx * rlen : 1.f;  // heading=atan2(0,0)=0 -> (1,0)
    const float hy = dy * rlen;                     // rlen=0 path gives hy=0

    float s = 0.f;   // sum of in-sight distances
    float cnt = 0.f; // in-sight count (incl. diagonal; fixed up below)

    const float4* __restrict__ p4 = (const float4*)pos; // 2 positions per load
    const int n2 = n >> 1;
#pragma unroll 4
    for (int j = lane; j < n2; j += 64) {
        const float4 p = p4[j];
        const float rx0 = p.x - pix, ry0 = p.y - piy;
        const float rx1 = p.z - pix, ry1 = p.w - piy;
        const float sq0 = rx0 * rx0 + ry0 * ry0;
        const float sq1 = rx1 * rx1 + ry1 * ry1;
        const float dist0 = __builtin_amdgcn_sqrtf(sq0);
        const float dist1 = __builtin_amdgcn_sqrtf(sq1);
        const float dot0 = rx0 * hx + ry0 * hy;
        const float dot1 = rx1 * hx + ry1 * hy;
        const bool in0 = dot0 >= COS_HALF_ANGLE * dist0;
        const bool in1 = dot1 >= COS_HALF_ANGLE * dist1;
        s += in0 ? dist0 : 0.f;
        cnt += in0 ? 1.f : 0.f;
        s += in1 ? dist1 : 0.f;
        cnt += in1 ? 1.f : 0.f;
    }

    // wave64 butterfly reduction
#pragma unroll
    for (int off = 32; off > 0; off >>= 1) {
        s += __shfl_xor(s, off, 64);
        cnt += __shfl_xor(cnt, off, 64);
    }

    if (lane == 0) {
        cnt -= 1.0f; // remove diagonal self-pair
        float mean = (cnt > 0.f) ? (s / fmaxf(cnt, 1.f)) : 0.f;
        mean = fminf(fmaxf(mean, MIN_D), MAX_D);
        const float reg = (mean - MIN_D) * (1.0f / (MAX_D - MIN_D));
        const float r = MIN_R + reg * (MAX_R - MIN_R);
        out[i] = indexes[i] ? r : all_radii[i];
    }
}

extern "C" void kernel_launch(void* const* d_in, const int* in_sizes, int n_in,
                              void* d_out, int out_size, void* d_ws, size_t ws_size,
                              hipStream_t stream) {
    const float* past      = (const float*)d_in[0];
    const float* pos       = (const float*)d_in[1];
    const int*   indexes   = (const int*)d_in[2];
    const float* all_radii = (const float*)d_in[3];
    float* out = (float*)d_out;

    const int n = in_sizes[1] / 2; // ped_positions is [n,2]
    const int blocks = (n + 3) / 4; // 4 waves/block, one wave per row
    arc_radius_kernel<<<blocks, 256, 0, stream>>>(past, pos, indexes, all_radii,
                                                  out, n);
}

// Round 2
// 82.987 us; speedup vs baseline: 1.0073x; 1.0073x over previous
//
#include <hip/hip_runtime.h>

// ArcShapeRadiusConfigVisibleNeighDist — N=8192 pairwise visible-neighbour
// mean distance -> radius regression.
//
// Math: in_sight = wrap(atan2(rel)-heading) in [-35deg,35deg)
//   <=>  (rel . h_unit) >= cos(35deg)*|rel|   (measure-zero boundary diff).
// Diagonal j==i passes (0>=0, dist 0); subtract 1 from count post-reduction.
//
// R2 change: stage all positions (64 KB) in LDS once per block.  R1 streamed
// pos from L2 every iteration (64 KB > 32 KB L1 -> cyclic thrash), and all
// CUs swept the same addresses in lockstep -> L2 hotspot.  LDS BW (128 B/clk/CU)
// has 2x headroom over the loop's 64 B/clk demand.
// Shape: 1024-thr blocks (16 waves, 1 row/wave), 512 blocks = 2 blocks/CU,
// 64 KB LDS x2 fits the 160 KB pool, 2048 thr/CU = full 8 waves/SIMD.

constexpr float COS_HALF_ANGLE = 0.8191520442889918f; // cos(35 deg)
constexpr float MIN_R = 0.5f, MAX_R = 4.0f;
constexpr float MIN_D = 0.2f, MAX_D = 5.0f;

__global__ __launch_bounds__(1024, 8) void arc_radius_kernel(
    const float* __restrict__ past,
    const float* __restrict__ pos,
    const int* __restrict__ indexes,
    const float* __restrict__ all_radii,
    float* __restrict__ out,
    int n)
{
    __shared__ float4 lds4[4096];           // 64 KB: all n=8192 positions
    const int tid = threadIdx.x;
    const int n2 = n >> 1;                  // float4 entries (2 positions each)
    const float4* __restrict__ p4 = (const float4*)pos;
    for (int k = tid; k < n2; k += 1024)
        lds4[k] = p4[k];

    const int lane = tid & 63;
    const int wave = tid >> 6;
    const int i = blockIdx.x * 16 + wave;   // one wave per output row

    // heading unit vector for row i (wave-uniform scalar loads; before sync
    // so the latency hides under the staging loop)
    float pix = 0.f, piy = 0.f, hx = 1.f, hy = 0.f;
    if (i < n) {
        pix = pos[2 * i + 0];
        piy = pos[2 * i + 1];
        const float dx = pix - past[2 * i + 0];
        const float dy = piy - past[2 * i + 1];
        const float d2 = dx * dx + dy * dy;
        const float rlen = (d2 > 0.f) ? __builtin_amdgcn_rsqf(d2) : 0.f;
        hx = (d2 > 0.f) ? dx * rlen : 1.f;  // atan2(0,0)=0 -> heading (1,0)
        hy = dy * rlen;
    }

    __syncthreads();
    if (i >= n) return;

    float s = 0.f;   // sum of in-sight distances
    float cnt = 0.f; // in-sight count (incl. diagonal; fixed up below)

#pragma unroll 4
    for (int j = lane; j < n2; j += 64) {
        const float4 p = lds4[j];           // ds_read_b128, stride-16B: clean
        const float rx0 = p.x - pix, ry0 = p.y - piy;
        const float rx1 = p.z - pix, ry1 = p.w - piy;
        const float sq0 = rx0 * rx0 + ry0 * ry0;
        const float sq1 = rx1 * rx1 + ry1 * ry1;
        const float dist0 = __builtin_amdgcn_sqrtf(sq0);
        const float dist1 = __builtin_amdgcn_sqrtf(sq1);
        const float dot0 = rx0 * hx + ry0 * hy;
        const float dot1 = rx1 * hx + ry1 * hy;
        const bool in0 = dot0 >= COS_HALF_ANGLE * dist0;
        const bool in1 = dot1 >= COS_HALF_ANGLE * dist1;
        s += in0 ? dist0 : 0.f;
        cnt += in0 ? 1.f : 0.f;
        s += in1 ? dist1 : 0.f;
        cnt += in1 ? 1.f : 0.f;
    }

    // wave64 butterfly reduction
#pragma unroll
    for (int off = 32; off > 0; off >>= 1) {
        s += __shfl_xor(s, off, 64);
        cnt += __shfl_xor(cnt, off, 64);
    }

    if (lane == 0) {
        cnt -= 1.0f; // remove diagonal self-pair
        float mean = (cnt > 0.f) ? (s / fmaxf(cnt, 1.f)) : 0.f;
        mean = fminf(fmaxf(mean, MIN_D), MAX_D);
        const float reg = (mean - MIN_D) * (1.0f / (MAX_D - MIN_D));
        const float r = MIN_R + reg * (MAX_R - MIN_R);
        out[i] = indexes[i] ? r : all_radii[i];
    }
}

extern "C" void kernel_launch(void* const* d_in, const int* in_sizes, int n_in,
                              void* d_out, int out_size, void* d_ws, size_t ws_size,
                              hipStream_t stream) {
    const float* past      = (const float*)d_in[0];
    const float* pos       = (const float*)d_in[1];
    const int*   indexes   = (const int*)d_in[2];
    const float* all_radii = (const float*)d_in[3];
    float* out = (float*)d_out;

    const int n = in_sizes[1] / 2;          // ped_positions is [n,2]
    const int blocks = (n + 15) / 16;       // 16 waves/block, one wave per row
    arc_radius_kernel<<<blocks, 1024, 0, stream>>>(past, pos, indexes, all_radii,
                                                   out, n);
}

// Round 3
// 79.254 us; speedup vs baseline: 1.0548x; 1.0471x over previous
//
#include <hip/hip_runtime.h>

// ArcShapeRadiusConfigVisibleNeighDist — N=8192 pairwise visible-neighbour
// mean distance -> radius regression.
//
// Math: in_sight = wrap(atan2(rel)-heading) in [-35deg,35deg)
//   <=>  (rel . h_unit) >= cos(35deg)*|rel|   (measure-zero boundary diff).
// Diagonal j==i passes (0>=0, dist 0); subtract 1 from count post-reduction.
//
// R3 change: packed fp32 math.  R1 (L2-stream) and R2 (LDS) timed identically
// -> kernel is VALU-issue-bound, not memory-bound.  gfx950 VOP3P has
// v_pk_{fma,add,mul}_f32 (2 fp32 per 2-cyc issue).  To get natural register
// pairs with no shuffles, LDS layout is SoA (xs[], ys[]); a ds_read_b128 of
// xs gives {x0,x1},{x2,x3} pairs directly.  Arithmetic uses ext_vector float2
// so LLVM forms v_pk ops.  cnt is int (carry-add).  ~28 two-cyc VALU + 4 sqrt
// per 4 pairs/lane vs ~52+4 scalar before -> ~1.45x fewer issue cycles.

typedef float f2 __attribute__((ext_vector_type(2)));

constexpr float COS_HALF_ANGLE = 0.8191520442889918f; // cos(35 deg)
constexpr float MIN_R = 0.5f, MAX_R = 4.0f;
constexpr float MIN_D = 0.2f, MAX_D = 5.0f;

__global__ __launch_bounds__(1024, 8) void arc_radius_kernel(
    const float* __restrict__ past,
    const float* __restrict__ pos,
    const int* __restrict__ indexes,
    const float* __restrict__ all_radii,
    float* __restrict__ out,
    int n)
{
    __shared__ alignas(16) float xs[8192];
    __shared__ alignas(16) float ys[8192];

    const int tid = threadIdx.x;
    const float4* __restrict__ p4 = (const float4*)pos; // {x0,y0,x1,y1}
    const int nq = n >> 1; // float4 count
    for (int k = tid; k < nq; k += 1024) {
        const float4 p = p4[k];
        xs[2 * k]     = p.x;
        xs[2 * k + 1] = p.z;
        ys[2 * k]     = p.y;
        ys[2 * k + 1] = p.w;
    }

    const int lane = tid & 63;
    const int wave = tid >> 6;
    const int i = blockIdx.x * 16 + wave;   // one wave per output row

    // heading unit vector for row i (wave-uniform; issued before the sync so
    // latency hides under staging)
    float pix = 0.f, piy = 0.f, hx = 1.f, hy = 0.f;
    if (i < n) {
        pix = pos[2 * i + 0];
        piy = pos[2 * i + 1];
        const float dx = pix - past[2 * i + 0];
        const float dy = piy - past[2 * i + 1];
        const float d2 = dx * dx + dy * dy;
        const float rlen = (d2 > 0.f) ? __builtin_amdgcn_rsqf(d2) : 0.f;
        hx = (d2 > 0.f) ? dx * rlen : 1.f;  // atan2(0,0)=0 -> heading (1,0)
        hy = dy * rlen;
    }

    __syncthreads();
    if (i >= n) return;

    const f2 pix2 = {pix, pix}, piy2 = {piy, piy};
    const f2 hx2 = {hx, hx}, hy2 = {hy, hy};
    const f2 negc2 = {-COS_HALF_ANGLE, -COS_HALF_ANGLE};

    f2 sa = {0.f, 0.f}, sb = {0.f, 0.f}; // two packed accumulators (ILP)
    int cnt = 0;

    const float4* __restrict__ x4 = (const float4*)xs; // n/4 entries
    const float4* __restrict__ y4 = (const float4*)ys;
    const int n4 = n >> 2;

#pragma unroll 2
    for (int j = lane; j < n4; j += 64) {
        const float4 xv = x4[j];            // ds_read_b128: {x0,x1,x2,x3}
        const float4 yv = y4[j];
        const f2 xa = {xv.x, xv.y}, xb = {xv.z, xv.w};
        const f2 ya = {yv.x, yv.y}, yb = {yv.z, yv.w};

        const f2 rxa = xa - pix2, rxb = xb - pix2;   // v_pk_add (neg mod)
        const f2 rya = ya - piy2, ryb = yb - piy2;

        f2 sqa = rxa * rxa;  sqa += rya * rya;       // pk_mul + pk_fma
        f2 sqb = rxb * rxb;  sqb += ryb * ryb;

        f2 da, db;                                   // per-element sqrt
        da.x = __builtin_amdgcn_sqrtf(sqa.x);
        da.y = __builtin_amdgcn_sqrtf(sqa.y);
        db.x = __builtin_amdgcn_sqrtf(sqb.x);
        db.y = __builtin_amdgcn_sqrtf(sqb.y);

        f2 dota = rxa * hx2;  dota += rya * hy2;     // pk_mul + pk_fma
        f2 dotb = rxb * hx2;  dotb += ryb * hy2;

        f2 diffa = dota;  diffa += negc2 * da;       // pk_fma: dot - c*dist
        f2 diffb = dotb;  diffb += negc2 * db;

        const bool i0 = diffa.x >= 0.f, i1 = diffa.y >= 0.f;
        const bool i2 = diffb.x >= 0.f, i3 = diffb.y >= 0.f;

        f2 ma, mb;
        ma.x = i0 ? da.x : 0.f;  ma.y = i1 ? da.y : 0.f;
        mb.x = i2 ? db.x : 0.f;  mb.y = i3 ? db.y : 0.f;
        sa += ma;                                    // pk_add
        sb += mb;
        cnt += (int)i0 + (int)i1 + (int)i2 + (int)i3;
    }

    float s = (sa.x + sa.y) + (sb.x + sb.y);
    float cntf = (float)cnt;

    // wave64 butterfly reduction
#pragma unroll
    for (int off = 32; off > 0; off >>= 1) {
        s += __shfl_xor(s, off, 64);
        cntf += __shfl_xor(cntf, off, 64);
    }

    if (lane == 0) {
        cntf -= 1.0f; // remove diagonal self-pair
        float mean = (cntf > 0.f) ? (s / fmaxf(cntf, 1.f)) : 0.f;
        mean = fminf(fmaxf(mean, MIN_D), MAX_D);
        const float reg = (mean - MIN_D) * (1.0f / (MAX_D - MIN_D));
        const float r = MIN_R + reg * (MAX_R - MIN_R);
        out[i] = indexes[i] ? r : all_radii[i];
    }
}

extern "C" void kernel_launch(void* const* d_in, const int* in_sizes, int n_in,
                              void* d_out, int out_size, void* d_ws, size_t ws_size,
                              hipStream_t stream) {
    const float* past      = (const float*)d_in[0];
    const float* pos       = (const float*)d_in[1];
    const int*   indexes   = (const int*)d_in[2];
    const float* all_radii = (const float*)d_in[3];
    float* out = (float*)d_out;

    const int n = in_sizes[1] / 2;          // ped_positions is [n,2]
    const int blocks = (n + 15) / 16;       // 16 waves/block, one wave per row
    arc_radius_kernel<<<blocks, 1024, 0, stream>>>(past, pos, indexes, all_radii,
                                                   out, n);
}